// Round 16
// baseline (300.459 us; speedup 1.0000x reference)
//
#include <hip/hip_runtime.h>
#include <hip/hip_fp16.h>

// Problem constants (from reference)
#define NN 50000
#define NE 1000000
#define FIN0 30
#define C 64
#define ED 11
#define NG 1024
#define DOUT 256
#define NBIN 196            // ceil(NN/256)
#define NGB 196             // grow blocks
#define PA_EDGES 1024       // edges per partition block (4/thread); 512 & 2048 both slower

typedef unsigned long long ull;

// ---- fused: bin histogram (1M dst) + graph rowptr from sorted batch + sw dots ----
__global__ __launch_bounds__(256) void histgrow_kernel(const int* __restrict__ dst,
    int* __restrict__ bcnt, const int* __restrict__ batch, int* __restrict__ growptr,
    const float* __restrict__ We0, const float* __restrict__ ae0,
    const float* __restrict__ We,  const float* __restrict__ ae,
    float* __restrict__ swg){
  int t=threadIdx.x;
  if(blockIdx.x<1024){
    __shared__ int h[256];
    h[t]=0;
    __syncthreads();
    for(int i=blockIdx.x*256+t;i<NE;i+=1024*256)
      atomicAdd(&h[dst[i]>>8],1);
    __syncthreads();
    if(h[t]) atomicAdd(&bcnt[t],h[t]);
  } else if(blockIdx.x<1024+NGB){
    int i=(int)(blockIdx.x-1024)*256+t;
    if(i>=NN) return;
    int bi=batch[i];
    int bp=(i==0)?-1:batch[i-1];
    for(int g=bp+1;g<=bi;++g) growptr[g]=i;
    if(i==NN-1){ for(int g=bi+1;g<=NG;++g) growptr[g]=NN; }
  } else {
    // one block: precompute sw[l*ED+j] = dot(We_l[j,:], ae_l) once (was per part-block)
    if(t<4*ED){
      int l=t/ED, j=t%ED;
      const float* wp=(l==0)? (We0+(size_t)j*C) : (We+((size_t)(l-1)*ED+j)*C);
      const float* ap=(l==0)? ae0 : (ae+(size_t)(l-1)*C);
      float s=0.f;
      for(int c=0;c<C;++c) s+=wp[c]*ap[c];
      swg[t]=s;
    }
  }
}

// single block: exclusive scan of 256 bin counts -> bbase (197 used) + gcur copy
__global__ __launch_bounds__(256) void scan196_kernel(const int* __restrict__ bcnt,
    int* __restrict__ bbase, int* __restrict__ gcur){
  __shared__ int p[256];
  int t=threadIdx.x;
  int v=bcnt[t];
  p[t]=v; __syncthreads();
  #pragma unroll
  for(int off=1;off<256;off<<=1){
    int u=(t>=off)?p[t-off]:0;
    __syncthreads(); p[t]+=u; __syncthreads();
  }
  int ex=p[t]-v;
  if(t<=NBIN) bbase[t]=ex;
  if(t<NBIN)  gcur[t]=ex;
}

// ---------------- Pass A v4: float4-staged edge_attr, low-barrier counting sort ----------------
__global__ __launch_bounds__(256) void part_kernel(const int* __restrict__ dst,
    const int* __restrict__ src, const float* __restrict__ edge_attr,
    const float* __restrict__ swg, int* __restrict__ gcur, uint4* __restrict__ prec){
  __shared__ uint4 lrec[PA_EDGES];           // 16KB
  __shared__ float tile[256*ED];             // 11KB (one 256-edge chunk, packed rows)
  __shared__ float sw[4*ED];
  __shared__ int hist[256], sc[256], lofs[256], bb[256];
  __shared__ int wsum[4];
  int t=threadIdx.x;
  hist[t]=0;
  if(t<4*ED) sw[t]=swg[t];
  __syncthreads();
  size_t e0=(size_t)blockIdx.x*PA_EDGES;
  int cnt=(int)min((size_t)PA_EDGES,(size_t)NE-e0);
  int dreg[4], sreg[4];
  #pragma unroll
  for(int r=0;r<4;++r){
    int i=r*256+t;
    if(i<cnt){
      dreg[r]=dst[e0+i]; sreg[r]=src[e0+i];
      atomicAdd(&hist[dreg[r]>>8],1);
    } else dreg[r]=-1;
  }
  __syncthreads();
  // wave-level scan of 256 bins (2 barriers total)
  int v=hist[t];
  int inc=v;
  #pragma unroll
  for(int off=1;off<64;off<<=1){
    int u=__shfl_up(inc,off,64);
    if((t&63)>=off) inc+=u;
  }
  if((t&63)==63) wsum[t>>6]=inc;
  __syncthreads();
  int woff=0;
  int myw=t>>6;
  #pragma unroll
  for(int k=0;k<3;++k) if(k<myw) woff+=wsum[k];
  int ex=woff+inc-v;
  sc[t]=ex;
  lofs[t]=ex;
  bb[t]=(v>0)?atomicAdd(&gcur[t],v):0;
  __syncthreads();
  // 4 chunks of 256 edges: coalesced float4 stage -> dot from LDS -> place bin-sorted
  #pragma unroll
  for(int r=0;r<4;++r){
    int cbase=r*256;
    int ccnt=cnt-cbase; if(ccnt>256) ccnt=256;
    if(ccnt>0){
      const float* eab=edge_attr+(e0+cbase)*(size_t)ED;  // chunk base: 16B-aligned
      int nf=ccnt*ED;
      int nf4=nf>>2;
      const float4* eab4=(const float4*)eab;
      for(int i=t;i<nf4;i+=256) ((float4*)tile)[i]=eab4[i];
      for(int i=nf4*4+t;i<nf;i+=256) tile[i]=eab[i];
    }
    __syncthreads();
    if(t<ccnt){
      const float* ea=&tile[t*ED];   // stride 11 across lanes: 2-way bank alias = free
      float d0=0,d1=0,d2=0,d3=0;
      #pragma unroll
      for(int j=0;j<ED;++j){
        float ev=ea[j];
        d0=fmaf(ev,sw[j],d0);
        d1=fmaf(ev,sw[ED+j],d1);
        d2=fmaf(ev,sw[2*ED+j],d2);
        d3=fmaf(ev,sw[3*ED+j],d3);
      }
      uint4 rec;
      rec.x=(unsigned)dreg[r]; rec.y=(unsigned)sreg[r];
      rec.z=(unsigned)__half_as_ushort(__float2half(d0))
           |((unsigned)__half_as_ushort(__float2half(d1))<<16);
      rec.w=(unsigned)__half_as_ushort(__float2half(d2))
           |((unsigned)__half_as_ushort(__float2half(d3))<<16);
      int slot=atomicAdd(&lofs[dreg[r]>>8],1);
      lrec[slot]=rec;
    }
    __syncthreads();                 // tile reused next chunk; lrec complete before flush
  }
  // coalesced flush (bin recomputed from record)
  for(int i=t;i<cnt;i+=256){
    uint4 rec=lrec[i];
    int b=(int)(rec.x>>8);
    int g=bb[b]+i-sc[b];
    prec[g]=rec;
  }
}

// ---------------- Pass B: bin -> exact CSR slots; also emits rowptr ----------------
__global__ __launch_bounds__(256) void build_kernel(const uint4* __restrict__ prec,
    const int* __restrict__ bbase,
    int* __restrict__ rowptr, int* __restrict__ src_csr, ushort* __restrict__ edch){
  __shared__ int cnt[256], cur[256];
  __shared__ int wsum[4];
  int t=threadIdx.x, b=blockIdx.x;
  int n0=b<<8;
  cnt[t]=0;
  __syncthreads();
  int beg=bbase[b], endd=bbase[b+1];
  for(int j=beg+t;j<endd;j+=256)
    atomicAdd(&cnt[(int)prec[j].x-n0],1);
  __syncthreads();
  int v=cnt[t];
  int inc=v;
  #pragma unroll
  for(int off=1;off<64;off<<=1){
    int u=__shfl_up(inc,off,64);
    if((t&63)>=off) inc+=u;
  }
  if((t&63)==63) wsum[t>>6]=inc;
  __syncthreads();
  int woff=0;
  int myw=t>>6;
  #pragma unroll
  for(int k=0;k<3;++k) if(k<myw) woff+=wsum[k];
  int ex=woff+inc-v;
  cur[t]=beg+ex;
  if(n0+t<NN) rowptr[n0+t]=beg+ex;
  if(b==0&&t==0) rowptr[NN]=NE;
  __syncthreads();
  for(int j=beg+t;j<endd;j+=256){
    uint4 r=prec[j];
    int d=(int)r.x, s=(int)r.y;
    int pos=atomicAdd(&cur[d-n0],1);
    src_csr[pos]=s;
    edch[pos]                =(ushort)(r.z&0xffffu);
    edch[(size_t)NE+pos]     =(ushort)(r.z>>16);
    edch[2*(size_t)NE+pos]   =(ushort)(r.w&0xffffu);
    edch[3*(size_t)NE+pos]   =(ushort)(r.w>>16);
  }
}

// ---------------- per-layer features: register-blocked vector GEMM ----------------
template<int FIN, int SXS>
__global__ __launch_bounds__(256) void feat_kernel(const float* __restrict__ in,
    const float* __restrict__ W, const float* __restrict__ Wres,
    const float* __restrict__ bvec, const float* __restrict__ av_src,
    const float* __restrict__ av_dst,
    __half* __restrict__ hW16, float* __restrict__ outb,
    float* __restrict__ as_, float* __restrict__ ad_){
  __shared__ float sW[FIN*C], sR[FIN*C];
  __shared__ float sx[64*SXS];
  __shared__ float sb[C], ss[C], sd[C];
  int tid=threadIdx.x;
  if(tid<C){ sb[tid]=bvec[tid]; ss[tid]=av_src[tid]; sd[tid]=av_dst[tid]; }
  for(int i=tid;i<FIN*C;i+=256){ sW[i]=W[i]; sR[i]=Wres[i]; }
  int nbase=blockIdx.x*64;
  int nvalid=min(64,NN-nbase);
  if constexpr (FIN==64){
    const float4* in4=(const float4*)(in+(size_t)nbase*64);
    for(int i=tid;i<1024;i+=256){
      int n=i>>4, k=(i&15)*4;
      float4 v=(n<nvalid)?in4[i]:make_float4(0.f,0.f,0.f,0.f);
      *(float4*)&sx[n*SXS+k]=v;
    }
  } else {
    for(int i=tid;i<64*FIN;i+=256){
      int n=i/FIN, k=i-n*FIN;
      sx[n*SXS+k]=(n<nvalid)?in[(size_t)(nbase+n)*FIN+k]:0.f;
    }
  }
  __syncthreads();
  int w=tid>>6, lane=tid&63;
  int ng=lane>>4, cl=lane&15;
  int n0=w*16+ng*4;
  int c0=cl*4;
  float hw[4][4]={}, hr[4][4]={};
  const float* sxp=&sx[n0*SXS];
  #pragma unroll 2
  for(int k=0;k<FIN;k+=2){
    float4 wv0=*(const float4*)&sW[k*C+c0];
    float4 rv0=*(const float4*)&sR[k*C+c0];
    float4 wv1=*(const float4*)&sW[(k+1)*C+c0];
    float4 rv1=*(const float4*)&sR[(k+1)*C+c0];
    float2 x0=*(const float2*)&sxp[k];
    float2 x1=*(const float2*)&sxp[SXS+k];
    float2 x2=*(const float2*)&sxp[2*SXS+k];
    float2 x3=*(const float2*)&sxp[3*SXS+k];
    float xa[4]={x0.x,x1.x,x2.x,x3.x};
    float xb[4]={x0.y,x1.y,x2.y,x3.y};
    #pragma unroll
    for(int r=0;r<4;++r){
      hw[r][0]=fmaf(xa[r],wv0.x,hw[r][0]);
      hw[r][1]=fmaf(xa[r],wv0.y,hw[r][1]);
      hw[r][2]=fmaf(xa[r],wv0.z,hw[r][2]);
      hw[r][3]=fmaf(xa[r],wv0.w,hw[r][3]);
      hr[r][0]=fmaf(xa[r],rv0.x,hr[r][0]);
      hr[r][1]=fmaf(xa[r],rv0.y,hr[r][1]);
      hr[r][2]=fmaf(xa[r],rv0.z,hr[r][2]);
      hr[r][3]=fmaf(xa[r],rv0.w,hr[r][3]);
      hw[r][0]=fmaf(xb[r],wv1.x,hw[r][0]);
      hw[r][1]=fmaf(xb[r],wv1.y,hw[r][1]);
      hw[r][2]=fmaf(xb[r],wv1.z,hw[r][2]);
      hw[r][3]=fmaf(xb[r],wv1.w,hw[r][3]);
      hr[r][0]=fmaf(xb[r],rv1.x,hr[r][0]);
      hr[r][1]=fmaf(xb[r],rv1.y,hr[r][1]);
      hr[r][2]=fmaf(xb[r],rv1.z,hr[r][2]);
      hr[r][3]=fmaf(xb[r],rv1.w,hr[r][3]);
    }
  }
  float s0=ss[c0], s1=ss[c0+1], s2=ss[c0+2], s3=ss[c0+3];
  float d0=sd[c0], d1=sd[c0+1], d2=sd[c0+2], d3=sd[c0+3];
  float b0v=sb[c0], b1v=sb[c0+1], b2v=sb[c0+2], b3v=sb[c0+3];
  #pragma unroll
  for(int r=0;r<4;++r){
    int n=n0+r;
    float ps=hw[r][0]*s0+hw[r][1]*s1+hw[r][2]*s2+hw[r][3]*s3;
    float pd=hw[r][0]*d0+hw[r][1]*d1+hw[r][2]*d2+hw[r][3]*d3;
    #pragma unroll
    for(int off=1;off<16;off<<=1){ ps+=__shfl_xor(ps,off,64); pd+=__shfl_xor(pd,off,64); }
    if(n<nvalid){
      size_t gn=(size_t)(nbase+n);
      ushort4 hv;
      hv.x=__half_as_ushort(__float2half(hw[r][0]));
      hv.y=__half_as_ushort(__float2half(hw[r][1]));
      hv.z=__half_as_ushort(__float2half(hw[r][2]));
      hv.w=__half_as_ushort(__float2half(hw[r][3]));
      *(ushort4*)&hW16[gn*C+c0]=hv;
      float4 ov;
      ov.x=hr[r][0]+b0v; ov.y=hr[r][1]+b1v; ov.z=hr[r][2]+b2v; ov.w=hr[r][3]+b3v;
      *(float4*)&outb[gn*C+c0]=ov;
      if(cl==0){ as_[gn]=ps; ad_[gn]=pd; }
    }
  }
}

// ------- fused alpha + softmax aggregation (best: 2 nodes/wave, single pass) -------
__device__ __forceinline__ void acc8(float* a, float at, uint4 u){
  __half2 h0=*(__half2*)&u.x, h1=*(__half2*)&u.y, h2=*(__half2*)&u.z, h3=*(__half2*)&u.w;
  float2 f0=__half22float2(h0), f1=__half22float2(h1);
  float2 f2=__half22float2(h2), f3=__half22float2(h3);
  a[0]=fmaf(at,f0.x,a[0]); a[1]=fmaf(at,f0.y,a[1]);
  a[2]=fmaf(at,f1.x,a[2]); a[3]=fmaf(at,f1.y,a[3]);
  a[4]=fmaf(at,f2.x,a[4]); a[5]=fmaf(at,f2.y,a[5]);
  a[6]=fmaf(at,f3.x,a[6]); a[7]=fmaf(at,f3.y,a[7]);
}

__global__ __launch_bounds__(256) void agg_kernel(const int* __restrict__ rowptr,
    const int* __restrict__ src_csr, const ushort* __restrict__ edc_l,
    const float* __restrict__ as_, const float* __restrict__ ad_,
    const __half* __restrict__ hW16, float* __restrict__ outb, int relu){
  __shared__ float2 sws[4][64];
  int w=threadIdx.x>>6, lane=threadIdx.x&63;
  int half=lane>>5, hl=lane&31;
  int n0=blockIdx.x*8+w*2;            // NN%8==0: always in range
  int nidx=n0+half;
  int beg=rowptr[nidx], end=rowptr[nidx+1];
  int deg=end-beg;
  const uint4* hw4=(const uint4*)hW16;   // row = 8 uint4 (8 halves each)

  if(__all(deg<=32)){
    float ad_n=ad_[nidx];
    int j=beg+hl;
    float al=-INFINITY; int sl=0;
    if(hl<deg){
      sl=src_csr[j];
      float a=as_[sl]+ad_n+__half2float(__ushort_as_half(edc_l[j]));
      al=(a>0.f)?a:0.2f*a;               // leaky_relu 0.2
    }
    float mn=al;
    #pragma unroll
    for(int off=16;off;off>>=1) mn=fmaxf(mn,__shfl_xor(mn,off,64));
    float wl=(hl<deg)?__expf(al-mn):0.f;
    float s=wl;
    #pragma unroll
    for(int off=16;off;off>>=1) s+=__shfl_xor(s,off,64);
    float2 pr; pr.x=wl; pr.y=__int_as_float(sl);
    sws[w][lane]=pr;                     // wave-private: no barrier
    int g=hl>>3, gl=hl&7;
    float acc[8]={0.f,0.f,0.f,0.f,0.f,0.f,0.f,0.f};
    int base=half*32;
    int t=g;
    for(; t+4<deg; t+=8){
      float2 r0=sws[w][base+t], r1=sws[w][base+t+4];
      uint4 u0=hw4[(size_t)__float_as_int(r0.y)*8+gl];
      uint4 u1=hw4[(size_t)__float_as_int(r1.y)*8+gl];
      acc8(acc,r0.x,u0);
      acc8(acc,r1.x,u1);
    }
    if(t<deg){
      float2 r=sws[w][base+t];
      uint4 u=hw4[(size_t)__float_as_int(r.y)*8+gl];
      acc8(acc,r.x,u);
    }
    #pragma unroll
    for(int off=8;off<=16;off<<=1){
      #pragma unroll
      for(int i=0;i<8;++i) acc[i]+=__shfl_xor(acc[i],off,64);
    }
    if(hl<8){
      float denom=s+1e-16f;
      size_t o0=(size_t)nidx*C+hl*8;
      float4 oa=*(float4*)&outb[o0];
      float4 ob=*(float4*)&outb[o0+4];
      float4 va,vb;
      va.x=acc[0]/denom+oa.x; va.y=acc[1]/denom+oa.y;
      va.z=acc[2]/denom+oa.z; va.w=acc[3]/denom+oa.w;
      vb.x=acc[4]/denom+ob.x; vb.y=acc[5]/denom+ob.y;
      vb.z=acc[6]/denom+ob.z; vb.w=acc[7]/denom+ob.w;
      if(relu){
        va.x=(va.x>0.f)?va.x:0.01f*va.x; va.y=(va.y>0.f)?va.y:0.01f*va.y;
        va.z=(va.z>0.f)?va.z:0.01f*va.z; va.w=(va.w>0.f)?va.w:0.01f*va.w;
        vb.x=(vb.x>0.f)?vb.x:0.01f*vb.x; vb.y=(vb.y>0.f)?vb.y:0.01f*vb.y;
        vb.z=(vb.z>0.f)?vb.z:0.01f*vb.z; vb.w=(vb.w>0.f)?vb.w:0.01f*vb.w;
      }
      *(float4*)&outb[o0]=va;
      *(float4*)&outb[o0+4]=vb;
    }
    return;
  }

  // ---- fallback: whole wave per node, 2 nodes sequentially (rare) ----
  for(int h=0;h<2;++h){
    int m=n0+h;
    int bh=__shfl(beg,h*32,64);
    int dh=__shfl(deg,h*32,64);
    float ad_n=ad_[m];
    int g2=lane>>3, gl2=lane&7;
    float s=0.f;
    float acc[8]={0.f,0.f,0.f,0.f,0.f,0.f,0.f,0.f};
    if(dh<=64){
      int j=bh+lane;
      float al=-INFINITY; int sl=0;
      if(lane<dh){
        sl=src_csr[j];
        float a=as_[sl]+ad_n+__half2float(__ushort_as_half(edc_l[j]));
        al=(a>0.f)?a:0.2f*a;
      }
      float mn=al;
      #pragma unroll
      for(int off=32;off;off>>=1) mn=fmaxf(mn,__shfl_xor(mn,off,64));
      float wl=(lane<dh)?__expf(al-mn):0.f;
      s=wl;
      #pragma unroll
      for(int off=32;off;off>>=1) s+=__shfl_xor(s,off,64);
      float2 pr; pr.x=wl; pr.y=__int_as_float(sl);
      sws[w][lane]=pr;
      int t=g2;
      for(; t+8<dh; t+=16){
        float2 r0=sws[w][t], r1=sws[w][t+8];
        uint4 u0=hw4[(size_t)__float_as_int(r0.y)*8+gl2];
        uint4 u1=hw4[(size_t)__float_as_int(r1.y)*8+gl2];
        acc8(acc,r0.x,u0);
        acc8(acc,r1.x,u1);
      }
      if(t<dh){
        float2 r=sws[w][t];
        uint4 u=hw4[(size_t)__float_as_int(r.y)*8+gl2];
        acc8(acc,r.x,u);
      }
    } else {
      float m_=-INFINITY;
      for(int base=bh;base<bh+dh;base+=64){
        int j=base+lane;
        float al=-INFINITY; int sl=0;
        if(j<bh+dh){
          sl=src_csr[j];
          float a=as_[sl]+ad_n+__half2float(__ushort_as_half(edc_l[j]));
          al=(a>0.f)?a:0.2f*a;
        }
        float cm=al;
        #pragma unroll
        for(int off=32;off;off>>=1) cm=fmaxf(cm,__shfl_xor(cm,off,64));
        float mn=fmaxf(m_,cm);
        float scale=(m_==-INFINITY)?0.f:__expf(m_-mn);
        s*=scale;
        #pragma unroll
        for(int i=0;i<8;++i) acc[i]*=scale;
        float wl=(j<bh+dh)?__expf(al-mn):0.f;
        float cs=wl;
        #pragma unroll
        for(int off=32;off;off>>=1) cs+=__shfl_xor(cs,off,64);
        s+=cs; m_=mn;
        float2 pr; pr.x=wl; pr.y=__int_as_float(sl);
        sws[w][lane]=pr;
        int cnt=min(64,bh+dh-base);
        int t=g2;
        for(; t+8<cnt; t+=16){
          float2 r0=sws[w][t], r1=sws[w][t+8];
          uint4 u0=hw4[(size_t)__float_as_int(r0.y)*8+gl2];
          uint4 u1=hw4[(size_t)__float_as_int(r1.y)*8+gl2];
          acc8(acc,r0.x,u0);
          acc8(acc,r1.x,u1);
        }
        if(t<cnt){
          float2 r=sws[w][t];
          uint4 u=hw4[(size_t)__float_as_int(r.y)*8+gl2];
          acc8(acc,r.x,u);
        }
      }
    }
    #pragma unroll
    for(int off=8;off<64;off<<=1){
      #pragma unroll
      for(int i=0;i<8;++i) acc[i]+=__shfl_xor(acc[i],off,64);
    }
    if(g2==0){
      float denom=s+1e-16f;
      size_t o0=(size_t)m*C+gl2*8;
      float4 oa=*(float4*)&outb[o0];
      float4 ob=*(float4*)&outb[o0+4];
      float4 va,vb;
      va.x=acc[0]/denom+oa.x; va.y=acc[1]/denom+oa.y;
      va.z=acc[2]/denom+oa.z; va.w=acc[3]/denom+oa.w;
      vb.x=acc[4]/denom+ob.x; vb.y=acc[5]/denom+ob.y;
      vb.z=acc[6]/denom+ob.z; vb.w=acc[7]/denom+ob.w;
      if(relu){
        va.x=(va.x>0.f)?va.x:0.01f*va.x; va.y=(va.y>0.f)?va.y:0.01f*va.y;
        va.z=(va.z>0.f)?va.z:0.01f*va.z; va.w=(va.w>0.f)?va.w:0.01f*va.w;
        vb.x=(vb.x>0.f)?vb.x:0.01f*vb.x; vb.y=(vb.y>0.f)?vb.y:0.01f*vb.y;
        vb.z=(vb.z>0.f)?vb.z:0.01f*vb.z; vb.w=(vb.w>0.f)?vb.w:0.01f*vb.w;
      }
      *(float4*)&outb[o0]=va;
      *(float4*)&outb[o0+4]=vb;
    }
  }
}

// ---------------- fused pooling + final linear (one block per graph) ----------------
__global__ __launch_bounds__(256) void poolout_kernel(const float* __restrict__ h,
    const int* __restrict__ growptr, const float* __restrict__ Wout,
    const float* __restrict__ bout, float* __restrict__ out){
  __shared__ float sp[128];
  int t=threadIdx.x, g=blockIdx.x;
  int beg=growptr[g], end=growptr[g+1];
  if(t<64){
    float mx=-INFINITY, sm=0.f;
    for(int n=beg;n<end;++n){ float v=h[(size_t)n*C+t]; mx=fmaxf(mx,v); sm+=v; }
    int cnt=end-beg;
    float gm=(cnt==0)?0.f:mx;              // isfinite fix for empty graphs
    float mean=sm/fmaxf((float)cnt,1.f);
    gm=(gm>0.f)?gm:0.01f*gm;               // leaky_relu 0.01
    mean=(mean>0.f)?mean:0.01f*mean;
    sp[t]=gm; sp[64+t]=mean;
  }
  __syncthreads();
  float o=bout[t];
  for(int k=0;k<128;++k) o=fmaf(sp[k],Wout[k*DOUT+t],o);
  out[(size_t)g*DOUT+t]=o;
}

extern "C" void kernel_launch(void* const* d_in, const int* in_sizes, int n_in,
                              void* d_out, int out_size, void* d_ws, size_t ws_size,
                              hipStream_t stream){
  const float* x        =(const float*)d_in[0];
  const float* edge_attr=(const float*)d_in[1];
  const float* W0       =(const float*)d_in[2];
  const float* asrc0    =(const float*)d_in[3];
  const float* adst0    =(const float*)d_in[4];
  const float* We0      =(const float*)d_in[5];
  const float* ae0      =(const float*)d_in[6];
  const float* Wres0    =(const float*)d_in[7];
  const float* b0       =(const float*)d_in[8];
  const float* W        =(const float*)d_in[9];
  const float* asrc     =(const float*)d_in[10];
  const float* adst     =(const float*)d_in[11];
  const float* We       =(const float*)d_in[12];
  const float* ae       =(const float*)d_in[13];
  const float* Wres     =(const float*)d_in[14];
  const float* b        =(const float*)d_in[15];
  const float* Wout     =(const float*)d_in[16];
  const float* bout     =(const float*)d_in[17];
  const int* edge_index =(const int*)d_in[18];
  const int* batch_index=(const int*)d_in[19];
  const int* src=edge_index;
  const int* dst=edge_index+NE;

  // workspace carve (~49 MB, prec region reused by bufB)
  char* p=(char*)d_ws;
  auto take=[&](size_t bytes)->void*{ void* r=(void*)p; p+=(bytes+255)&~(size_t)255; return r; };
  int* rowptr  =(int*)take((size_t)(NN+1)*4);
  int* growptr =(int*)take((size_t)(NG+1)*4);
  int* bcnt    =(int*)take((size_t)256*4);
  int* bbase   =(int*)take((size_t)256*4);
  int* gcur    =(int*)take((size_t)256*4);
  float* swg   =(float*)take((size_t)256*4);
  int* src_csr =(int*)take((size_t)NE*4);
  float* as_   =(float*)take((size_t)NN*4);
  float* ad_   =(float*)take((size_t)NN*4);
  ushort* edch =(ushort*)take((size_t)NE*4*2);    // 4 layers x NE half, CSR order (SoA)
  __half* hW16 =(__half*)take((size_t)NN*C*2);
  float* bufA  =(float*)take((size_t)NN*C*4);
  // region: prec (16MB, dead after build) -> later bufB (12.8MB)
  uint4* prec  =(uint4*)take((size_t)NE*16);
  float* bufB  =(float*)prec;
  (void)ws_size; (void)in_sizes; (void)n_in; (void)out_size;

  hipMemsetAsync(bcnt,0,(size_t)256*4,stream);
  histgrow_kernel<<<1024+NGB+1,256,0,stream>>>(dst,bcnt,batch_index,growptr,
      We0,ae0,We,ae,swg);
  scan196_kernel<<<1,256,0,stream>>>(bcnt,bbase,gcur);

  part_kernel<<<(NE+PA_EDGES-1)/PA_EDGES,256,0,stream>>>(dst,src,edge_attr,
      swg,gcur,prec);
  build_kernel<<<NBIN,256,0,stream>>>(prec,bbase,rowptr,src_csr,edch);

  const int nblkF=(NN+63)/64;      // 782
  const int nblkA=NN/8;            // 6250 (NN%8==0)
  // layer 0 (F=30, sx stride 36)
  feat_kernel<FIN0,36><<<nblkF,256,0,stream>>>(x,W0,Wres0,b0,asrc0,adst0,hW16,bufA,as_,ad_);
  agg_kernel<<<nblkA,256,0,stream>>>(rowptr,src_csr,edch,as_,ad_,hW16,bufA,1);
  // layers 1..3 (ping-pong; sx stride 68)
  float* bin=bufA; float* bo=bufB;
  for(int i=0;i<3;++i){
    feat_kernel<C,68><<<nblkF,256,0,stream>>>(bin,W+(size_t)i*C*C,Wres+(size_t)i*C*C,
        b+(size_t)i*C,asrc+(size_t)i*C,adst+(size_t)i*C,hW16,bo,as_,ad_);
    agg_kernel<<<nblkA,256,0,stream>>>(rowptr,src_csr,edch+(size_t)(i+1)*NE,as_,ad_,hW16,bo,(i<2)?1:0);
    float* t=bin; bin=bo; bo=t;
  }
  poolout_kernel<<<NG,256,0,stream>>>(bin,growptr,Wout,bout,(float*)d_out);
}

// Round 17
// 298.407 us; speedup vs baseline: 1.0069x; 1.0069x over previous
//
#include <hip/hip_runtime.h>
#include <hip/hip_fp16.h>

// Problem constants (from reference)
#define NN 50000
#define NE 1000000
#define FIN0 30
#define C 64
#define ED 11
#define NG 1024
#define DOUT 256
#define NBIN 196            // ceil(NN/256)
#define NGB 196             // grow blocks
#define PA_EDGES 1024       // edges per partition block (4/thread); 512/2048 & f4-tile all slower

typedef unsigned long long ull;

// ---- fused: bin histogram (1M dst) + graph rowptr from sorted batch + sw dots ----
__global__ __launch_bounds__(256) void histgrow_kernel(const int* __restrict__ dst,
    int* __restrict__ bcnt, const int* __restrict__ batch, int* __restrict__ growptr,
    const float* __restrict__ We0, const float* __restrict__ ae0,
    const float* __restrict__ We,  const float* __restrict__ ae,
    float* __restrict__ swg){
  int t=threadIdx.x;
  if(blockIdx.x<1024){
    __shared__ int h[256];
    h[t]=0;
    __syncthreads();
    for(int i=blockIdx.x*256+t;i<NE;i+=1024*256)
      atomicAdd(&h[dst[i]>>8],1);
    __syncthreads();
    if(h[t]) atomicAdd(&bcnt[t],h[t]);
  } else if(blockIdx.x<1024+NGB){
    int i=(int)(blockIdx.x-1024)*256+t;
    if(i>=NN) return;
    int bi=batch[i];
    int bp=(i==0)?-1:batch[i-1];
    for(int g=bp+1;g<=bi;++g) growptr[g]=i;
    if(i==NN-1){ for(int g=bi+1;g<=NG;++g) growptr[g]=NN; }
  } else {
    // one block: precompute sw[l*ED+j] = dot(We_l[j,:], ae_l)
    if(t<4*ED){
      int l=t/ED, j=t%ED;
      const float* wp=(l==0)? (We0+(size_t)j*C) : (We+((size_t)(l-1)*ED+j)*C);
      const float* ap=(l==0)? ae0 : (ae+(size_t)(l-1)*C);
      float s=0.f;
      for(int c=0;c<C;++c) s+=wp[c]*ap[c];
      swg[t]=s;
    }
  }
}

// single block: exclusive scan of 256 bin counts -> bbase (197 used) + gcur copy
__global__ __launch_bounds__(256) void scan196_kernel(const int* __restrict__ bcnt,
    int* __restrict__ bbase, int* __restrict__ gcur){
  __shared__ int p[256];
  int t=threadIdx.x;
  int v=bcnt[t];
  p[t]=v; __syncthreads();
  #pragma unroll
  for(int off=1;off<256;off<<=1){
    int u=(t>=off)?p[t-off]:0;
    __syncthreads(); p[t]+=u; __syncthreads();
  }
  int ex=p[t]-v;
  if(t<=NBIN) bbase[t]=ex;
  if(t<NBIN)  gcur[t]=ex;
}

// ---------------- Pass A (r15 best): direct scalar edge_attr reads ----------------
__global__ __launch_bounds__(256) void part_kernel(const int* __restrict__ dst,
    const int* __restrict__ src, const float* __restrict__ edge_attr,
    const float* __restrict__ swg, int* __restrict__ gcur, uint4* __restrict__ prec){
  __shared__ uint4 lrec[PA_EDGES];           // 16KB
  __shared__ float sw[4*ED];
  __shared__ int hist[256], sc[256], lofs[256], bb[256];
  __shared__ int wsum[4];
  int t=threadIdx.x;
  hist[t]=0;
  if(t<4*ED) sw[t]=swg[t];
  __syncthreads();
  size_t e0=(size_t)blockIdx.x*PA_EDGES;
  int cnt=(int)min((size_t)PA_EDGES,(size_t)NE-e0);
  int dreg[4], sreg[4];
  #pragma unroll
  for(int r=0;r<4;++r){
    int i=r*256+t;
    if(i<cnt){
      dreg[r]=dst[e0+i]; sreg[r]=src[e0+i];
      atomicAdd(&hist[dreg[r]>>8],1);
    } else dreg[r]=-1;
  }
  __syncthreads();
  // wave-level scan of 256 bins (2 barriers total)
  int v=hist[t];
  int inc=v;
  #pragma unroll
  for(int off=1;off<64;off<<=1){
    int u=__shfl_up(inc,off,64);
    if((t&63)>=off) inc+=u;
  }
  if((t&63)==63) wsum[t>>6]=inc;
  __syncthreads();
  int woff=0;
  int myw=t>>6;
  #pragma unroll
  for(int k=0;k<3;++k) if(k<myw) woff+=wsum[k];
  int ex=woff+inc-v;
  sc[t]=ex;
  lofs[t]=ex;
  bb[t]=(v>0)?atomicAdd(&gcur[t],v):0;
  __syncthreads();
  // place records bin-sorted into LDS (ed dots computed from direct reads)
  #pragma unroll
  for(int r=0;r<4;++r){
    int i=r*256+t;
    if(i<cnt){
      const float* ea=edge_attr+(e0+i)*(size_t)ED;
      float d0=0,d1=0,d2=0,d3=0;
      #pragma unroll
      for(int j=0;j<ED;++j){
        float ev=ea[j];
        d0=fmaf(ev,sw[j],d0);
        d1=fmaf(ev,sw[ED+j],d1);
        d2=fmaf(ev,sw[2*ED+j],d2);
        d3=fmaf(ev,sw[3*ED+j],d3);
      }
      uint4 rec;
      rec.x=(unsigned)dreg[r]; rec.y=(unsigned)sreg[r];
      rec.z=(unsigned)__half_as_ushort(__float2half(d0))
           |((unsigned)__half_as_ushort(__float2half(d1))<<16);
      rec.w=(unsigned)__half_as_ushort(__float2half(d2))
           |((unsigned)__half_as_ushort(__float2half(d3))<<16);
      int slot=atomicAdd(&lofs[dreg[r]>>8],1);
      lrec[slot]=rec;
    }
  }
  __syncthreads();
  // coalesced flush (bin recomputed from record)
  for(int i=t;i<cnt;i+=256){
    uint4 rec=lrec[i];
    int b=(int)(rec.x>>8);
    int g=bb[b]+i-sc[b];
    prec[g]=rec;
  }
}

// ---------------- Pass B: bin -> exact CSR slots; also emits rowptr ----------------
__global__ __launch_bounds__(256) void build_kernel(const uint4* __restrict__ prec,
    const int* __restrict__ bbase,
    int* __restrict__ rowptr, int* __restrict__ src_csr, ushort* __restrict__ edch){
  __shared__ int cnt[256], cur[256];
  __shared__ int wsum[4];
  int t=threadIdx.x, b=blockIdx.x;
  int n0=b<<8;
  cnt[t]=0;
  __syncthreads();
  int beg=bbase[b], endd=bbase[b+1];
  for(int j=beg+t;j<endd;j+=256)
    atomicAdd(&cnt[(int)prec[j].x-n0],1);
  __syncthreads();
  int v=cnt[t];
  int inc=v;
  #pragma unroll
  for(int off=1;off<64;off<<=1){
    int u=__shfl_up(inc,off,64);
    if((t&63)>=off) inc+=u;
  }
  if((t&63)==63) wsum[t>>6]=inc;
  __syncthreads();
  int woff=0;
  int myw=t>>6;
  #pragma unroll
  for(int k=0;k<3;++k) if(k<myw) woff+=wsum[k];
  int ex=woff+inc-v;
  cur[t]=beg+ex;
  if(n0+t<NN) rowptr[n0+t]=beg+ex;
  if(b==0&&t==0) rowptr[NN]=NE;
  __syncthreads();
  for(int j=beg+t;j<endd;j+=256){
    uint4 r=prec[j];
    int d=(int)r.x, s=(int)r.y;
    int pos=atomicAdd(&cur[d-n0],1);
    src_csr[pos]=s;
    edch[pos]                =(ushort)(r.z&0xffffu);
    edch[(size_t)NE+pos]     =(ushort)(r.z>>16);
    edch[2*(size_t)NE+pos]   =(ushort)(r.w&0xffffu);
    edch[3*(size_t)NE+pos]   =(ushort)(r.w>>16);
  }
}

// ---------------- per-layer features: register-blocked vector GEMM ----------------
template<int FIN, int SXS>
__global__ __launch_bounds__(256) void feat_kernel(const float* __restrict__ in,
    const float* __restrict__ W, const float* __restrict__ Wres,
    const float* __restrict__ bvec, const float* __restrict__ av_src,
    const float* __restrict__ av_dst,
    __half* __restrict__ hW16, float* __restrict__ outb,
    float* __restrict__ as_, float* __restrict__ ad_){
  __shared__ float sW[FIN*C], sR[FIN*C];
  __shared__ float sx[64*SXS];
  __shared__ float sb[C], ss[C], sd[C];
  int tid=threadIdx.x;
  if(tid<C){ sb[tid]=bvec[tid]; ss[tid]=av_src[tid]; sd[tid]=av_dst[tid]; }
  for(int i=tid;i<FIN*C;i+=256){ sW[i]=W[i]; sR[i]=Wres[i]; }
  int nbase=blockIdx.x*64;
  int nvalid=min(64,NN-nbase);
  if constexpr (FIN==64){
    const float4* in4=(const float4*)(in+(size_t)nbase*64);
    for(int i=tid;i<1024;i+=256){
      int n=i>>4, k=(i&15)*4;
      float4 v=(n<nvalid)?in4[i]:make_float4(0.f,0.f,0.f,0.f);
      *(float4*)&sx[n*SXS+k]=v;
    }
  } else {
    for(int i=tid;i<64*FIN;i+=256){
      int n=i/FIN, k=i-n*FIN;
      sx[n*SXS+k]=(n<nvalid)?in[(size_t)(nbase+n)*FIN+k]:0.f;
    }
  }
  __syncthreads();
  int w=tid>>6, lane=tid&63;
  int ng=lane>>4, cl=lane&15;
  int n0=w*16+ng*4;
  int c0=cl*4;
  float hw[4][4]={}, hr[4][4]={};
  const float* sxp=&sx[n0*SXS];
  #pragma unroll 2
  for(int k=0;k<FIN;k+=2){
    float4 wv0=*(const float4*)&sW[k*C+c0];
    float4 rv0=*(const float4*)&sR[k*C+c0];
    float4 wv1=*(const float4*)&sW[(k+1)*C+c0];
    float4 rv1=*(const float4*)&sR[(k+1)*C+c0];
    float2 x0=*(const float2*)&sxp[k];
    float2 x1=*(const float2*)&sxp[SXS+k];
    float2 x2=*(const float2*)&sxp[2*SXS+k];
    float2 x3=*(const float2*)&sxp[3*SXS+k];
    float xa[4]={x0.x,x1.x,x2.x,x3.x};
    float xb[4]={x0.y,x1.y,x2.y,x3.y};
    #pragma unroll
    for(int r=0;r<4;++r){
      hw[r][0]=fmaf(xa[r],wv0.x,hw[r][0]);
      hw[r][1]=fmaf(xa[r],wv0.y,hw[r][1]);
      hw[r][2]=fmaf(xa[r],wv0.z,hw[r][2]);
      hw[r][3]=fmaf(xa[r],wv0.w,hw[r][3]);
      hr[r][0]=fmaf(xa[r],rv0.x,hr[r][0]);
      hr[r][1]=fmaf(xa[r],rv0.y,hr[r][1]);
      hr[r][2]=fmaf(xa[r],rv0.z,hr[r][2]);
      hr[r][3]=fmaf(xa[r],rv0.w,hr[r][3]);
      hw[r][0]=fmaf(xb[r],wv1.x,hw[r][0]);
      hw[r][1]=fmaf(xb[r],wv1.y,hw[r][1]);
      hw[r][2]=fmaf(xb[r],wv1.z,hw[r][2]);
      hw[r][3]=fmaf(xb[r],wv1.w,hw[r][3]);
      hr[r][0]=fmaf(xb[r],rv1.x,hr[r][0]);
      hr[r][1]=fmaf(xb[r],rv1.y,hr[r][1]);
      hr[r][2]=fmaf(xb[r],rv1.z,hr[r][2]);
      hr[r][3]=fmaf(xb[r],rv1.w,hr[r][3]);
    }
  }
  float s0=ss[c0], s1=ss[c0+1], s2=ss[c0+2], s3=ss[c0+3];
  float d0=sd[c0], d1=sd[c0+1], d2=sd[c0+2], d3=sd[c0+3];
  float b0v=sb[c0], b1v=sb[c0+1], b2v=sb[c0+2], b3v=sb[c0+3];
  #pragma unroll
  for(int r=0;r<4;++r){
    int n=n0+r;
    float ps=hw[r][0]*s0+hw[r][1]*s1+hw[r][2]*s2+hw[r][3]*s3;
    float pd=hw[r][0]*d0+hw[r][1]*d1+hw[r][2]*d2+hw[r][3]*d3;
    #pragma unroll
    for(int off=1;off<16;off<<=1){ ps+=__shfl_xor(ps,off,64); pd+=__shfl_xor(pd,off,64); }
    if(n<nvalid){
      size_t gn=(size_t)(nbase+n);
      ushort4 hv;
      hv.x=__half_as_ushort(__float2half(hw[r][0]));
      hv.y=__half_as_ushort(__float2half(hw[r][1]));
      hv.z=__half_as_ushort(__float2half(hw[r][2]));
      hv.w=__half_as_ushort(__float2half(hw[r][3]));
      *(ushort4*)&hW16[gn*C+c0]=hv;
      float4 ov;
      ov.x=hr[r][0]+b0v; ov.y=hr[r][1]+b1v; ov.z=hr[r][2]+b2v; ov.w=hr[r][3]+b3v;
      *(float4*)&outb[gn*C+c0]=ov;
      if(cl==0){ as_[gn]=ps; ad_[gn]=pd; }
    }
  }
}

// ------- fused alpha + softmax aggregation (best: 2 nodes/wave, single pass) -------
__device__ __forceinline__ void acc8(float* a, float at, uint4 u){
  __half2 h0=*(__half2*)&u.x, h1=*(__half2*)&u.y, h2=*(__half2*)&u.z, h3=*(__half2*)&u.w;
  float2 f0=__half22float2(h0), f1=__half22float2(h1);
  float2 f2=__half22float2(h2), f3=__half22float2(h3);
  a[0]=fmaf(at,f0.x,a[0]); a[1]=fmaf(at,f0.y,a[1]);
  a[2]=fmaf(at,f1.x,a[2]); a[3]=fmaf(at,f1.y,a[3]);
  a[4]=fmaf(at,f2.x,a[4]); a[5]=fmaf(at,f2.y,a[5]);
  a[6]=fmaf(at,f3.x,a[6]); a[7]=fmaf(at,f3.y,a[7]);
}

__global__ __launch_bounds__(256) void agg_kernel(const int* __restrict__ rowptr,
    const int* __restrict__ src_csr, const ushort* __restrict__ edc_l,
    const float* __restrict__ as_, const float* __restrict__ ad_,
    const __half* __restrict__ hW16, float* __restrict__ outb, int relu){
  __shared__ float2 sws[4][64];
  int w=threadIdx.x>>6, lane=threadIdx.x&63;
  int half=lane>>5, hl=lane&31;
  int n0=blockIdx.x*8+w*2;            // NN%8==0: always in range
  int nidx=n0+half;
  int beg=rowptr[nidx], end=rowptr[nidx+1];
  int deg=end-beg;
  const uint4* hw4=(const uint4*)hW16;   // row = 8 uint4 (8 halves each)

  if(__all(deg<=32)){
    float ad_n=ad_[nidx];
    int j=beg+hl;
    float al=-INFINITY; int sl=0;
    if(hl<deg){
      sl=src_csr[j];
      float a=as_[sl]+ad_n+__half2float(__ushort_as_half(edc_l[j]));
      al=(a>0.f)?a:0.2f*a;               // leaky_relu 0.2
    }
    float mn=al;
    #pragma unroll
    for(int off=16;off;off>>=1) mn=fmaxf(mn,__shfl_xor(mn,off,64));
    float wl=(hl<deg)?__expf(al-mn):0.f;
    float s=wl;
    #pragma unroll
    for(int off=16;off;off>>=1) s+=__shfl_xor(s,off,64);
    float2 pr; pr.x=wl; pr.y=__int_as_float(sl);
    sws[w][lane]=pr;                     // wave-private: no barrier
    int g=hl>>3, gl=hl&7;
    float acc[8]={0.f,0.f,0.f,0.f,0.f,0.f,0.f,0.f};
    int base=half*32;
    int t=g;
    for(; t+4<deg; t+=8){
      float2 r0=sws[w][base+t], r1=sws[w][base+t+4];
      uint4 u0=hw4[(size_t)__float_as_int(r0.y)*8+gl];
      uint4 u1=hw4[(size_t)__float_as_int(r1.y)*8+gl];
      acc8(acc,r0.x,u0);
      acc8(acc,r1.x,u1);
    }
    if(t<deg){
      float2 r=sws[w][base+t];
      uint4 u=hw4[(size_t)__float_as_int(r.y)*8+gl];
      acc8(acc,r.x,u);
    }
    #pragma unroll
    for(int off=8;off<=16;off<<=1){
      #pragma unroll
      for(int i=0;i<8;++i) acc[i]+=__shfl_xor(acc[i],off,64);
    }
    if(hl<8){
      float denom=s+1e-16f;
      size_t o0=(size_t)nidx*C+hl*8;
      float4 oa=*(float4*)&outb[o0];
      float4 ob=*(float4*)&outb[o0+4];
      float4 va,vb;
      va.x=acc[0]/denom+oa.x; va.y=acc[1]/denom+oa.y;
      va.z=acc[2]/denom+oa.z; va.w=acc[3]/denom+oa.w;
      vb.x=acc[4]/denom+ob.x; vb.y=acc[5]/denom+ob.y;
      vb.z=acc[6]/denom+ob.z; vb.w=acc[7]/denom+ob.w;
      if(relu){
        va.x=(va.x>0.f)?va.x:0.01f*va.x; va.y=(va.y>0.f)?va.y:0.01f*va.y;
        va.z=(va.z>0.f)?va.z:0.01f*va.z; va.w=(va.w>0.f)?va.w:0.01f*va.w;
        vb.x=(vb.x>0.f)?vb.x:0.01f*vb.x; vb.y=(vb.y>0.f)?vb.y:0.01f*vb.y;
        vb.z=(vb.z>0.f)?vb.z:0.01f*vb.z; vb.w=(vb.w>0.f)?vb.w:0.01f*vb.w;
      }
      *(float4*)&outb[o0]=va;
      *(float4*)&outb[o0+4]=vb;
    }
    return;
  }

  // ---- fallback: whole wave per node, 2 nodes sequentially (rare) ----
  for(int h=0;h<2;++h){
    int m=n0+h;
    int bh=__shfl(beg,h*32,64);
    int dh=__shfl(deg,h*32,64);
    float ad_n=ad_[m];
    int g2=lane>>3, gl2=lane&7;
    float s=0.f;
    float acc[8]={0.f,0.f,0.f,0.f,0.f,0.f,0.f,0.f};
    if(dh<=64){
      int j=bh+lane;
      float al=-INFINITY; int sl=0;
      if(lane<dh){
        sl=src_csr[j];
        float a=as_[sl]+ad_n+__half2float(__ushort_as_half(edc_l[j]));
        al=(a>0.f)?a:0.2f*a;
      }
      float mn=al;
      #pragma unroll
      for(int off=32;off;off>>=1) mn=fmaxf(mn,__shfl_xor(mn,off,64));
      float wl=(lane<dh)?__expf(al-mn):0.f;
      s=wl;
      #pragma unroll
      for(int off=32;off;off>>=1) s+=__shfl_xor(s,off,64);
      float2 pr; pr.x=wl; pr.y=__int_as_float(sl);
      sws[w][lane]=pr;
      int t=g2;
      for(; t+8<dh; t+=16){
        float2 r0=sws[w][t], r1=sws[w][t+8];
        uint4 u0=hw4[(size_t)__float_as_int(r0.y)*8+gl2];
        uint4 u1=hw4[(size_t)__float_as_int(r1.y)*8+gl2];
        acc8(acc,r0.x,u0);
        acc8(acc,r1.x,u1);
      }
      if(t<dh){
        float2 r=sws[w][t];
        uint4 u=hw4[(size_t)__float_as_int(r.y)*8+gl2];
        acc8(acc,r.x,u);
      }
    } else {
      float m_=-INFINITY;
      for(int base=bh;base<bh+dh;base+=64){
        int j=base+lane;
        float al=-INFINITY; int sl=0;
        if(j<bh+dh){
          sl=src_csr[j];
          float a=as_[sl]+ad_n+__half2float(__ushort_as_half(edc_l[j]));
          al=(a>0.f)?a:0.2f*a;
        }
        float cm=al;
        #pragma unroll
        for(int off=32;off;off>>=1) cm=fmaxf(cm,__shfl_xor(cm,off,64));
        float mn=fmaxf(m_,cm);
        float scale=(m_==-INFINITY)?0.f:__expf(m_-mn);
        s*=scale;
        #pragma unroll
        for(int i=0;i<8;++i) acc[i]*=scale;
        float wl=(j<bh+dh)?__expf(al-mn):0.f;
        float cs=wl;
        #pragma unroll
        for(int off=32;off;off>>=1) cs+=__shfl_xor(cs,off,64);
        s+=cs; m_=mn;
        float2 pr; pr.x=wl; pr.y=__int_as_float(sl);
        sws[w][lane]=pr;
        int cnt=min(64,bh+dh-base);
        int t=g2;
        for(; t+8<cnt; t+=16){
          float2 r0=sws[w][t], r1=sws[w][t+8];
          uint4 u0=hw4[(size_t)__float_as_int(r0.y)*8+gl2];
          uint4 u1=hw4[(size_t)__float_as_int(r1.y)*8+gl2];
          acc8(acc,r0.x,u0);
          acc8(acc,r1.x,u1);
        }
        if(t<cnt){
          float2 r=sws[w][t];
          uint4 u=hw4[(size_t)__float_as_int(r.y)*8+gl2];
          acc8(acc,r.x,u);
        }
      }
    }
    #pragma unroll
    for(int off=8;off<64;off<<=1){
      #pragma unroll
      for(int i=0;i<8;++i) acc[i]+=__shfl_xor(acc[i],off,64);
    }
    if(g2==0){
      float denom=s+1e-16f;
      size_t o0=(size_t)m*C+gl2*8;
      float4 oa=*(float4*)&outb[o0];
      float4 ob=*(float4*)&outb[o0+4];
      float4 va,vb;
      va.x=acc[0]/denom+oa.x; va.y=acc[1]/denom+oa.y;
      va.z=acc[2]/denom+oa.z; va.w=acc[3]/denom+oa.w;
      vb.x=acc[4]/denom+ob.x; vb.y=acc[5]/denom+ob.y;
      vb.z=acc[6]/denom+ob.z; vb.w=acc[7]/denom+ob.w;
      if(relu){
        va.x=(va.x>0.f)?va.x:0.01f*va.x; va.y=(va.y>0.f)?va.y:0.01f*va.y;
        va.z=(va.z>0.f)?va.z:0.01f*va.z; va.w=(va.w>0.f)?va.w:0.01f*va.w;
        vb.x=(vb.x>0.f)?vb.x:0.01f*vb.x; vb.y=(vb.y>0.f)?vb.y:0.01f*vb.y;
        vb.z=(vb.z>0.f)?vb.z:0.01f*vb.z; vb.w=(vb.w>0.f)?vb.w:0.01f*vb.w;
      }
      *(float4*)&outb[o0]=va;
      *(float4*)&outb[o0+4]=vb;
    }
  }
}

// ---------------- fused pooling + final linear (one block per graph) ----------------
__global__ __launch_bounds__(256) void poolout_kernel(const float* __restrict__ h,
    const int* __restrict__ growptr, const float* __restrict__ Wout,
    const float* __restrict__ bout, float* __restrict__ out){
  __shared__ float sp[128];
  int t=threadIdx.x, g=blockIdx.x;
  int beg=growptr[g], end=growptr[g+1];
  if(t<64){
    float mx=-INFINITY, sm=0.f;
    for(int n=beg;n<end;++n){ float v=h[(size_t)n*C+t]; mx=fmaxf(mx,v); sm+=v; }
    int cnt=end-beg;
    float gm=(cnt==0)?0.f:mx;              // isfinite fix for empty graphs
    float mean=sm/fmaxf((float)cnt,1.f);
    gm=(gm>0.f)?gm:0.01f*gm;               // leaky_relu 0.01
    mean=(mean>0.f)?mean:0.01f*mean;
    sp[t]=gm; sp[64+t]=mean;
  }
  __syncthreads();
  float o=bout[t];
  for(int k=0;k<128;++k) o=fmaf(sp[k],Wout[k*DOUT+t],o);
  out[(size_t)g*DOUT+t]=o;
}

extern "C" void kernel_launch(void* const* d_in, const int* in_sizes, int n_in,
                              void* d_out, int out_size, void* d_ws, size_t ws_size,
                              hipStream_t stream){
  const float* x        =(const float*)d_in[0];
  const float* edge_attr=(const float*)d_in[1];
  const float* W0       =(const float*)d_in[2];
  const float* asrc0    =(const float*)d_in[3];
  const float* adst0    =(const float*)d_in[4];
  const float* We0      =(const float*)d_in[5];
  const float* ae0      =(const float*)d_in[6];
  const float* Wres0    =(const float*)d_in[7];
  const float* b0       =(const float*)d_in[8];
  const float* W        =(const float*)d_in[9];
  const float* asrc     =(const float*)d_in[10];
  const float* adst     =(const float*)d_in[11];
  const float* We       =(const float*)d_in[12];
  const float* ae       =(const float*)d_in[13];
  const float* Wres     =(const float*)d_in[14];
  const float* b        =(const float*)d_in[15];
  const float* Wout     =(const float*)d_in[16];
  const float* bout     =(const float*)d_in[17];
  const int* edge_index =(const int*)d_in[18];
  const int* batch_index=(const int*)d_in[19];
  const int* src=edge_index;
  const int* dst=edge_index+NE;

  // workspace carve (~49 MB, prec region reused by bufB)
  char* p=(char*)d_ws;
  auto take=[&](size_t bytes)->void*{ void* r=(void*)p; p+=(bytes+255)&~(size_t)255; return r; };
  int* rowptr  =(int*)take((size_t)(NN+1)*4);
  int* growptr =(int*)take((size_t)(NG+1)*4);
  int* bcnt    =(int*)take((size_t)256*4);
  int* bbase   =(int*)take((size_t)256*4);
  int* gcur    =(int*)take((size_t)256*4);
  float* swg   =(float*)take((size_t)256*4);
  int* src_csr =(int*)take((size_t)NE*4);
  float* as_   =(float*)take((size_t)NN*4);
  float* ad_   =(float*)take((size_t)NN*4);
  ushort* edch =(ushort*)take((size_t)NE*4*2);    // 4 layers x NE half, CSR order (SoA)
  __half* hW16 =(__half*)take((size_t)NN*C*2);
  float* bufA  =(float*)take((size_t)NN*C*4);
  // region: prec (16MB, dead after build) -> later bufB (12.8MB)
  uint4* prec  =(uint4*)take((size_t)NE*16);
  float* bufB  =(float*)prec;
  (void)ws_size; (void)in_sizes; (void)n_in; (void)out_size;

  hipMemsetAsync(bcnt,0,(size_t)256*4,stream);
  histgrow_kernel<<<1024+NGB+1,256,0,stream>>>(dst,bcnt,batch_index,growptr,
      We0,ae0,We,ae,swg);
  scan196_kernel<<<1,256,0,stream>>>(bcnt,bbase,gcur);

  part_kernel<<<(NE+PA_EDGES-1)/PA_EDGES,256,0,stream>>>(dst,src,edge_attr,
      swg,gcur,prec);
  build_kernel<<<NBIN,256,0,stream>>>(prec,bbase,rowptr,src_csr,edch);

  const int nblkF=(NN+63)/64;      // 782
  const int nblkA=NN/8;            // 6250 (NN%8==0)
  // layer 0 (F=30, sx stride 36)
  feat_kernel<FIN0,36><<<nblkF,256,0,stream>>>(x,W0,Wres0,b0,asrc0,adst0,hW16,bufA,as_,ad_);
  agg_kernel<<<nblkA,256,0,stream>>>(rowptr,src_csr,edch,as_,ad_,hW16,bufA,1);
  // layers 1..3 (ping-pong; sx stride 68)
  float* bin=bufA; float* bo=bufB;
  for(int i=0;i<3;++i){
    feat_kernel<C,68><<<nblkF,256,0,stream>>>(bin,W+(size_t)i*C*C,Wres+(size_t)i*C*C,
        b+(size_t)i*C,asrc+(size_t)i*C,adst+(size_t)i*C,hW16,bo,as_,ad_);
    agg_kernel<<<nblkA,256,0,stream>>>(rowptr,src_csr,edch+(size_t)(i+1)*NE,as_,ad_,hW16,bo,(i<2)?1:0);
    float* t=bin; bin=bo; bo=t;
  }
  poolout_kernel<<<NG,256,0,stream>>>(bin,growptr,Wout,bout,(float*)d_out);
}